// Round 6
// baseline (378.616 us; speedup 1.0000x reference)
//
#include <hip/hip_runtime.h>
#include <hip/hip_bf16.h>

typedef __attribute__((ext_vector_type(4))) float f32x4;
typedef __attribute__((ext_vector_type(8))) short bf16x8;

#define HW    16384   // 128*128
#define CDIM  256

__device__ __forceinline__ unsigned short f2bf(float x) {
    union { float f; unsigned u; } c; c.f = x;
    unsigned r = c.u + 0x7fffu + ((c.u >> 16) & 1u);   // RNE
    return (unsigned short)(r >> 16);
}
__device__ __forceinline__ float bf2f(unsigned short u) {
    union { unsigned u; float f; } c; c.u = ((unsigned)u) << 16;
    return c.f;
}

// A/B LDS tile: 128 rows x 64 k bf16, 128B rows.
// byte(row,k) = row*128 + ((k*2) ^ ((row&7)<<4))  -> measured 262K conflicts (R2).
__device__ __forceinline__ int tswz(int row, int kbyte) {
    return row * 128 + (kbyte ^ ((row & 7) << 4));
}

// F2t[pixel][c] = sum_k W1[c,k] * feat[k][pixel]  (bf16 out, channel-last)
// R2 kernel verbatim except __launch_bounds__(256,2) -> (256,4):
// 32KB LDS and 104 VGPR allow 4 blocks/CU; R2 ran only 2 (occupancy 21%).
// grid 2048 = 1024 m-tiles x 2 n-halves (n-half major; L3 absorbs 2nd feat pass).
__global__ __launch_bounds__(256, 4) void f2_gemm(
    const float* __restrict__ feat, const float* __restrict__ W1,
    unsigned short* __restrict__ f2t) {
    __shared__ short lds[16384];            // 32KB: A bytes [0,16384), B [16384,32768)
    char* const ldsc = (char*)lds;

    const int t      = threadIdx.x;
    const int m_tile = blockIdx.x & 1023;
    const int n_half = blockIdx.x >> 10;
    const int m_base = m_tile << 7;
    const float* fb  = feat + (size_t)(m_base >> 14) * CDIM * HW + (m_base & (HW - 1));
    const float* wb  = W1 + (size_t)(n_half * 128) * CDIM;

    const int lane = t & 63;
    const int wid  = t >> 6;
    const int wm   = wid >> 1;           // 2 m-slabs of 64
    const int wn   = wid & 1;            // 2 n-slabs of 64

    const int sm0 = (t >> 3) << 2;       // staging row base 0..124 (A:m, B:c)
    const int kb  = (t & 7) << 3;        // staging k base 0..56 (8 k/thread)

    f32x4 acc[4][4] = {};
    float av[8][4];                      // A raw: [dk][dm]
    float bv[4][8];                      // B raw: [dc][dk]

    auto load_tile = [&](int kk) {
        const float* fk = fb + (size_t)(kk * 64 + kb) * HW + sm0;
#pragma unroll
        for (int dk = 0; dk < 8; ++dk) {
            const float4 v = *reinterpret_cast<const float4*>(fk + (size_t)dk * HW);
            av[dk][0] = v.x; av[dk][1] = v.y; av[dk][2] = v.z; av[dk][3] = v.w;
        }
        const float* wk = wb + (size_t)sm0 * CDIM + kk * 64 + kb;
#pragma unroll
        for (int dc = 0; dc < 4; ++dc) {
            const float4 u = *reinterpret_cast<const float4*>(wk + (size_t)dc * CDIM);
            const float4 w = *reinterpret_cast<const float4*>(wk + (size_t)dc * CDIM + 4);
            bv[dc][0] = u.x; bv[dc][1] = u.y; bv[dc][2] = u.z; bv[dc][3] = u.w;
            bv[dc][4] = w.x; bv[dc][5] = w.y; bv[dc][6] = w.z; bv[dc][7] = w.w;
        }
    };

    auto write_tile = [&]() {
#pragma unroll
        for (int dm = 0; dm < 4; ++dm) {           // A: transpose in regs
            const int row = sm0 + dm;
            bf16x8 w;
#pragma unroll
            for (int dk = 0; dk < 8; ++dk) w[dk] = (short)f2bf(av[dk][dm]);
            *reinterpret_cast<bf16x8*>(ldsc + tswz(row, kb * 2)) = w;
        }
#pragma unroll
        for (int dc = 0; dc < 4; ++dc) {           // B: k already contiguous
            const int row = sm0 + dc;
            bf16x8 w;
#pragma unroll
            for (int dk = 0; dk < 8; ++dk) w[dk] = (short)f2bf(bv[dc][dk]);
            *reinterpret_cast<bf16x8*>(ldsc + 16384 + tswz(row, kb * 2)) = w;
        }
    };

    auto compute = [&]() {
#pragma unroll
        for (int ks = 0; ks < 2; ++ks) {
            const int kb2 = ks * 64 + ((lane >> 4) << 4);   // byte offset of k*2
            bf16x8 af[4], bfr[4];
#pragma unroll
            for (int mi = 0; mi < 4; ++mi) {
                const int row = wm * 64 + mi * 16 + (lane & 15);
                af[mi] = *reinterpret_cast<const bf16x8*>(ldsc + tswz(row, kb2));
            }
#pragma unroll
            for (int ni = 0; ni < 4; ++ni) {
                const int c = wn * 64 + ni * 16 + (lane & 15);
                bfr[ni] = *reinterpret_cast<const bf16x8*>(ldsc + 16384 + tswz(c, kb2));
            }
#pragma unroll
            for (int mi = 0; mi < 4; ++mi)
#pragma unroll
                for (int ni = 0; ni < 4; ++ni)
                    acc[mi][ni] = __builtin_amdgcn_mfma_f32_16x16x32_bf16(
                        af[mi], bfr[ni], acc[mi][ni], 0, 0, 0);
        }
    };

    // prologue
    load_tile(0);
    write_tile();
    __syncthreads();
    // main loop: issue k+1 loads before compute(k), convert/write after
    for (int kk = 0; kk < 4; ++kk) {
        if (kk < 3) load_tile(kk + 1);
        compute();
        __syncthreads();
        if (kk < 3) { write_tile(); __syncthreads(); }
    }

    // ---- epilogue: acc -> bf16 -> LDS (swizzled) -> coalesced dwordx4 stores
#pragma unroll
    for (int mi = 0; mi < 4; ++mi)
#pragma unroll
        for (int ni = 0; ni < 4; ++ni) {
            const int c2 = (wn * 64 + ni * 16 + (lane & 15)) * 2;
#pragma unroll
            for (int r = 0; r < 4; ++r) {
                const int row = wm * 64 + mi * 16 + ((lane >> 4) << 2) + r;
                *reinterpret_cast<unsigned short*>(
                    ldsc + row * 256 + (c2 ^ (((row >> 2) & 3) << 5))) =
                    f2bf(acc[mi][ni][r]);
            }
        }
    __syncthreads();
#pragma unroll
    for (int i = 0; i < 8; ++i) {
        const int row = ((t >> 4) << 3) + i;
        const int cb  = (t & 15) * 16;
        const int4 v = *reinterpret_cast<const int4*>(
            ldsc + row * 256 + (cb ^ (((row >> 2) & 3) << 5)));
        *reinterpret_cast<int4*>((char*)f2t +
            (size_t)(m_base + row) * 512 + n_half * 256 + cb) = v;
    }
}

// One wave per sample point: bilinear-weighted sum of 4 contiguous 512B rows
// of F2t, then relu(s+b1) . W2 -> 2 scalars, out = batch_edges + d.
__global__ __launch_bounds__(256) void point_kernel(
    const unsigned short* __restrict__ f2t,
    const float* __restrict__ be,
    const float* __restrict__ b1, const float* __restrict__ W2,
    float* __restrict__ out) {
    const int p    = (blockIdx.x * 256 + threadIdx.x) >> 6;   // 0..65535
    const int lane = threadIdx.x & 63;

    const float ex = be[p * 2 + 0];
    const float ey = be[p * 2 + 1];
    const float gx = ex * (2.0f / 128.0f) - 1.0f;
    const float gy = ey * (2.0f / 128.0f) - 1.0f;
    const float px = (gx + 1.0f) * 64.0f - 0.5f;
    const float py = (gy + 1.0f) * 64.0f - 0.5f;
    const float x0f = floorf(px), y0f = floorf(py);
    const int   x0 = (int)x0f, y0 = (int)y0f;
    const float wx1 = px - x0f, wy1 = py - y0f;
    const float wx0 = 1.0f - wx1, wy0 = 1.0f - wy1;

    const size_t pix_base = (size_t)(p >> 13) * HW;
    const int c0 = lane * 4;

    float s0 = 0.f, s1 = 0.f, s2 = 0.f, s3 = 0.f;
#pragma unroll
    for (int cy = 0; cy < 2; ++cy) {
        const int   yi  = y0 + cy;
        const float wy  = cy ? wy1 : wy0;
        const bool  yin = (yi >= 0) && (yi < 128);
        const int   yc  = min(max(yi, 0), 127);
#pragma unroll
        for (int cx = 0; cx < 2; ++cx) {
            const int   xi  = x0 + cx;
            const float wx  = cx ? wx1 : wx0;
            const bool  xin = (xi >= 0) && (xi < 128);
            const int   xc  = min(max(xi, 0), 127);
            const float w   = wx * wy * (float)(xin && yin);
            const ushort4 v = *reinterpret_cast<const ushort4*>(
                &f2t[(pix_base + (size_t)yc * 128 + xc) * 256 + c0]);
            s0 += w * bf2f(v.x); s1 += w * bf2f(v.y);
            s2 += w * bf2f(v.z); s3 += w * bf2f(v.w);
        }
    }
    const float4 bb  = *reinterpret_cast<const float4*>(&b1[c0]);
    const float4 w2a = *reinterpret_cast<const float4*>(&W2[c0]);
    const float4 w2b = *reinterpret_cast<const float4*>(&W2[256 + c0]);
    const float h0 = fmaxf(s0 + bb.x, 0.f);
    const float h1 = fmaxf(s1 + bb.y, 0.f);
    const float h2 = fmaxf(s2 + bb.z, 0.f);
    const float h3 = fmaxf(s3 + bb.w, 0.f);
    float a0 = h0 * w2a.x + h1 * w2a.y + h2 * w2a.z + h3 * w2a.w;
    float a1 = h0 * w2b.x + h1 * w2b.y + h2 * w2b.z + h3 * w2b.w;
#pragma unroll
    for (int off = 32; off > 0; off >>= 1) {
        a0 += __shfl_xor(a0, off);
        a1 += __shfl_xor(a1, off);
    }
    if (lane == 0) {
        out[p * 2 + 0] = ex + a0;
        out[p * 2 + 1] = ey + a1;
    }
}

extern "C" void kernel_launch(void* const* d_in, const int* in_sizes, int n_in,
                              void* d_out, int out_size, void* d_ws, size_t ws_size,
                              hipStream_t stream) {
    const float* feat = (const float*)d_in[0];
    const float* be   = (const float*)d_in[1];
    const float* W1   = (const float*)d_in[2];
    const float* b1   = (const float*)d_in[3];
    const float* W2   = (const float*)d_in[4];
    float* out = (float*)d_out;
    unsigned short* f2t = (unsigned short*)d_ws;   // 131072*256 bf16 = 64 MiB

    f2_gemm<<<2048, 256, 0, stream>>>(feat, W1, f2t);
    point_kernel<<<16384, 256, 0, stream>>>(f2t, be, b1, W2, out);
}

// Round 7
// 99.164 us; speedup vs baseline: 3.8181x; 3.8181x over previous
//
#include <hip/hip_runtime.h>
#include <hip/hip_bf16.h>

typedef __attribute__((ext_vector_type(4))) float f32x4;
typedef __attribute__((ext_vector_type(8))) short bf16x8;

#define HW    16384   // 128*128
#define CDIM  256

__device__ __forceinline__ unsigned short f2bf(float x) {
    union { float f; unsigned u; } c; c.f = x;
    unsigned r = c.u + 0x7fffu + ((c.u >> 16) & 1u);   // RNE
    return (unsigned short)(r >> 16);
}
__device__ __forceinline__ float bf2f(unsigned short u) {
    union { unsigned u; float f; } c; c.u = ((unsigned)u) << 16;
    return c.f;
}

// R2's measured-good tile layout: rows of 64 k bf16 = 128 B,
// byte(row,k) = row*128 + ((k*2) ^ ((row&7)<<4)).  262K conflicts total in R2.
__device__ __forceinline__ int tswz(int row, int kbyte) {
    return row * 128 + (kbyte ^ ((row & 7) << 4));
}

// F2t[px][c] = sum_k W1[c,k] * feat[k][px]  (bf16 out, channel-last)
// BM=128 px, BN=64 c, K=256 (4 steps of BK=64).
// Prologue: W1-quarter -> LDS (4 chunks of [64c][64k], tswz) -> 16 B-frags in
// VGPRs; LDS region then reused as A double-buffer (2 x [128px][64k], tswz).
// One barrier per K-step. Grid: R4's XCD-sibling map (FETCH measured 66 MB).
__global__ __launch_bounds__(256, 2) void f2_gemm(
    const float* __restrict__ feat, const float* __restrict__ W1,
    unsigned short* __restrict__ f2t) {
    __shared__ __attribute__((aligned(16))) char ldsc[32768];

    const int t    = threadIdx.x;
    const int lane = t & 63;
    const int wid  = t >> 6;
    const int kg   = lane >> 4;     // 0..3
    const int rr   = lane & 15;
    const int wm   = wid >> 1;      // 2 px-slabs of 64
    const int wn   = wid & 1;       // 2 c-slabs of 32

    // b = xcd + 8*nq + 32*j -> m = xcd*128 + j ; 4 nq-siblings share an XCD
    const int b      = blockIdx.x;
    const int m      = ((b & 7) << 7) | (b >> 5);
    const int nq     = (b >> 3) & 3;
    const int m_base = m << 7;
    const float* fb  = feat + (size_t)(m_base >> 14) * (CDIM * HW) + (m_base & (HW - 1));
    const float* wb  = W1 + (size_t)nq * 64 * CDIM;

    const int sm0 = (t >> 3) << 2;   // A staging: px-quad base 0..124
    const int kb  = (t & 7) << 3;    // staging k base (8 k per thread)

    // ---- prologue 1: stage W1-quarter into 4 LDS chunks of [64c][64k] ----
    {
        const int c0 = ((t >> 3) & 15) << 2;
#pragma unroll
        for (int r = 0; r < 2; ++r) {
            const int chunk = r * 2 + (t >> 7);
            const float* wp = wb + (size_t)c0 * CDIM + chunk * 64 + kb;
#pragma unroll
            for (int dc = 0; dc < 3 + 1; ++dc) {
                const float4 u = *reinterpret_cast<const float4*>(wp + (size_t)dc * CDIM);
                const float4 v = *reinterpret_cast<const float4*>(wp + (size_t)dc * CDIM + 4);
                bf16x8 w;
                w[0] = (short)f2bf(u.x); w[1] = (short)f2bf(u.y);
                w[2] = (short)f2bf(u.z); w[3] = (short)f2bf(u.w);
                w[4] = (short)f2bf(v.x); w[5] = (short)f2bf(v.y);
                w[6] = (short)f2bf(v.z); w[7] = (short)f2bf(v.w);
                *reinterpret_cast<bf16x8*>(
                    ldsc + chunk * 8192 + tswz(c0 + dc, kb * 2)) = w;
            }
        }
    }
    __syncthreads();

    // ---- prologue 2: each wave pulls its 16 B-fragments into registers ----
    bf16x8 bq[2][4][2];
#pragma unroll
    for (int ni = 0; ni < 2; ++ni) {
        const int c = wn * 32 + ni * 16 + rr;
#pragma unroll
        for (int kk = 0; kk < 4; ++kk)
#pragma unroll
            for (int ks = 0; ks < 2; ++ks)
                bq[ni][kk][ks] = *reinterpret_cast<const bf16x8*>(
                    ldsc + kk * 8192 + tswz(c, ks * 64 + (kg << 4)));
    }
    __syncthreads();   // B region is now dead; reuse as A double-buffer

    f32x4 acc[4][2] = {};
    float av[8][4];    // A staging regs: [dk][px-in-quad]

    auto load_a = [&](int kk) {
        const float* fk = fb + (size_t)(kk * 64 + kb) * HW + sm0;
#pragma unroll
        for (int dk = 0; dk < 8; ++dk) {
            const float4 v = *reinterpret_cast<const float4*>(fk + (size_t)dk * HW);
            av[dk][0] = v.x; av[dk][1] = v.y; av[dk][2] = v.z; av[dk][3] = v.w;
        }
    };
    auto write_a = [&](int lbuf) {
        char* base = ldsc + lbuf * 16384;
#pragma unroll
        for (int dm = 0; dm < 4; ++dm) {
            const int row = sm0 + dm;
            bf16x8 w;
#pragma unroll
            for (int dk = 0; dk < 8; ++dk) w[dk] = (short)f2bf(av[dk][dm]);
            *reinterpret_cast<bf16x8*>(base + tswz(row, kb * 2)) = w;
        }
    };

    load_a(0);
    write_a(0);
    __syncthreads();

    // ---- main loop: 4 K-steps, ONE barrier each; loads issued pre-compute ----
#pragma unroll
    for (int kk = 0; kk < 4; ++kk) {
        if (kk < 3) load_a(kk + 1);
        const char* ab = ldsc + (kk & 1) * 16384;
#pragma unroll
        for (int ks = 0; ks < 2; ++ks) {
            const int kb2 = ks * 64 + (kg << 4);
            bf16x8 af[4];
#pragma unroll
            for (int mi = 0; mi < 4; ++mi) {
                const int row = wm * 64 + mi * 16 + rr;
                af[mi] = *reinterpret_cast<const bf16x8*>(ab + tswz(row, kb2));
            }
#pragma unroll
            for (int mi = 0; mi < 4; ++mi)
#pragma unroll
                for (int ni = 0; ni < 2; ++ni)
                    acc[mi][ni] = __builtin_amdgcn_mfma_f32_16x16x32_bf16(
                        af[mi], bq[ni][kk][ks], acc[mi][ni], 0, 0, 0);
        }
        if (kk < 3) {
            write_a((kk + 1) & 1);   // other buffer than current readers'
            __syncthreads();
        }
    }

    // ---- epilogue: stage C-quarter [128px][64c bf16] in LDS, coalesced stores
    // (writes land in buf0 region; final compute read buf1 -> disjoint)
#pragma unroll
    for (int mi = 0; mi < 4; ++mi)
#pragma unroll
        for (int ni = 0; ni < 2; ++ni) {
            const int c2 = (wn * 32 + ni * 16 + rr) * 2;
#pragma unroll
            for (int r = 0; r < 4; ++r) {
                const int row = wm * 64 + mi * 16 + (kg << 2) + r;
                *reinterpret_cast<unsigned short*>(
                    ldsc + row * 128 + (c2 ^ (((row >> 2) & 3) << 4))) =
                    f2bf(acc[mi][ni][r]);
            }
        }
    __syncthreads();
#pragma unroll
    for (int i = 0; i < 4; ++i) {
        const int row = i * 32 + (t >> 3);
        const int cb  = (t & 7) * 16;
        const int4 v = *reinterpret_cast<const int4*>(
            ldsc + row * 128 + (cb ^ (((row >> 2) & 3) << 4)));
        *reinterpret_cast<int4*>((char*)f2t +
            (size_t)(m_base + row) * 512 + nq * 128 + cb) = v;
    }
}

// One wave per sample point: bilinear-weighted sum of 4 contiguous 512B rows
// of F2t, then relu(s+b1) . W2 -> 2 scalars, out = batch_edges + d.
__global__ __launch_bounds__(256) void point_kernel(
    const unsigned short* __restrict__ f2t,
    const float* __restrict__ be,
    const float* __restrict__ b1, const float* __restrict__ W2,
    float* __restrict__ out) {
    const int p    = (blockIdx.x * 256 + threadIdx.x) >> 6;   // 0..65535
    const int lane = threadIdx.x & 63;

    const float ex = be[p * 2 + 0];
    const float ey = be[p * 2 + 1];
    const float gx = ex * (2.0f / 128.0f) - 1.0f;
    const float gy = ey * (2.0f / 128.0f) - 1.0f;
    const float px = (gx + 1.0f) * 64.0f - 0.5f;
    const float py = (gy + 1.0f) * 64.0f - 0.5f;
    const float x0f = floorf(px), y0f = floorf(py);
    const int   x0 = (int)x0f, y0 = (int)y0f;
    const float wx1 = px - x0f, wy1 = py - y0f;
    const float wx0 = 1.0f - wx1, wy0 = 1.0f - wy1;

    const size_t pix_base = (size_t)(p >> 13) * HW;
    const int c0 = lane * 4;

    float s0 = 0.f, s1 = 0.f, s2 = 0.f, s3 = 0.f;
#pragma unroll
    for (int cy = 0; cy < 2; ++cy) {
        const int   yi  = y0 + cy;
        const float wy  = cy ? wy1 : wy0;
        const bool  yin = (yi >= 0) && (yi < 128);
        const int   yc  = min(max(yi, 0), 127);
#pragma unroll
        for (int cx = 0; cx < 2; ++cx) {
            const int   xi  = x0 + cx;
            const float wx  = cx ? wx1 : wx0;
            const bool  xin = (xi >= 0) && (xi < 128);
            const int   xc  = min(max(xi, 0), 127);
            const float w   = wx * wy * (float)(xin && yin);
            const ushort4 v = *reinterpret_cast<const ushort4*>(
                &f2t[(pix_base + (size_t)yc * 128 + xc) * 256 + c0]);
            s0 += w * bf2f(v.x); s1 += w * bf2f(v.y);
            s2 += w * bf2f(v.z); s3 += w * bf2f(v.w);
        }
    }
    const float4 bb  = *reinterpret_cast<const float4*>(&b1[c0]);
    const float4 w2a = *reinterpret_cast<const float4*>(&W2[c0]);
    const float4 w2b = *reinterpret_cast<const float4*>(&W2[256 + c0]);
    const float h0 = fmaxf(s0 + bb.x, 0.f);
    const float h1 = fmaxf(s1 + bb.y, 0.f);
    const float h2 = fmaxf(s2 + bb.z, 0.f);
    const float h3 = fmaxf(s3 + bb.w, 0.f);
    float a0 = h0 * w2a.x + h1 * w2a.y + h2 * w2a.z + h3 * w2a.w;
    float a1 = h0 * w2b.x + h1 * w2b.y + h2 * w2b.z + h3 * w2b.w;
#pragma unroll
    for (int off = 32; off > 0; off >>= 1) {
        a0 += __shfl_xor(a0, off);
        a1 += __shfl_xor(a1, off);
    }
    if (lane == 0) {
        out[p * 2 + 0] = ex + a0;
        out[p * 2 + 1] = ey + a1;
    }
}

extern "C" void kernel_launch(void* const* d_in, const int* in_sizes, int n_in,
                              void* d_out, int out_size, void* d_ws, size_t ws_size,
                              hipStream_t stream) {
    const float* feat = (const float*)d_in[0];
    const float* be   = (const float*)d_in[1];
    const float* W1   = (const float*)d_in[2];
    const float* b1   = (const float*)d_in[3];
    const float* W2   = (const float*)d_in[4];
    float* out = (float*)d_out;
    unsigned short* f2t = (unsigned short*)d_ws;   // 131072*256 bf16 = 64 MiB

    f2_gemm<<<4096, 256, 0, stream>>>(feat, W1, f2t);
    point_kernel<<<16384, 256, 0, stream>>>(f2t, be, b1, W2, out);
}

// Round 8
// 96.763 us; speedup vs baseline: 3.9128x; 1.0248x over previous
//
#include <hip/hip_runtime.h>
#include <hip/hip_bf16.h>

typedef __attribute__((ext_vector_type(4))) float f32x4;
typedef __attribute__((ext_vector_type(8))) short bf16x8;

#define HW    16384   // 128*128
#define CDIM  256

__device__ __forceinline__ unsigned short f2bf(float x) {
    union { float f; unsigned u; } c; c.f = x;
    unsigned r = c.u + 0x7fffu + ((c.u >> 16) & 1u);   // RNE
    return (unsigned short)(r >> 16);
}
__device__ __forceinline__ float bf2f(unsigned short u) {
    union { unsigned u; float f; } c; c.u = ((unsigned)u) << 16;
    return c.f;
}

// A LDS: [128 px][256 k] bf16, 512B rows, 16B-granule XOR swizzle.
// bank = f(granule only) since px*512 % 128 == 0; fragment reads: slots
// (kk*4+kg)^(px&7) span 8 granules x 4 kg = 32 banks -> conflict-free.
__device__ __forceinline__ int aswz(int px, int kbyte) {
    return px * 512 + (kbyte ^ ((px & 7) << 4));
}

// F2t[px][c] = sum_k W1[c,k] * feat[k][px]  (bf16 out, channel-last)
// Block: 256 thr = 4 waves; tile 128 px x 128 c (2 c-halves).
// Whole-K A staged once (64 KB LDS) -> ONE barrier -> 8 barrier-free
// ds_read+MFMA steps. B (32 c/wave x 256 k) in registers (R7-proven).
// Grid map: xcd = b&7; px_tile = xcd*128 + (b>>4); c_half = (b>>3)&1
// -> c-sibling pair adjacent on same XCD (R4-proven FETCH halving).
__global__ __launch_bounds__(256, 1) void f2_gemm(
    const float* __restrict__ feat, const float* __restrict__ W1,
    unsigned short* __restrict__ f2t) {
    __shared__ __attribute__((aligned(16))) char ldsc[65536];

    const int t    = threadIdx.x;
    const int lane = t & 63;
    const int wid  = t >> 6;
    const int rr   = lane & 15;
    const int kg   = lane >> 4;      // 0..3

    const int b       = blockIdx.x;
    const int px_tile = ((b & 7) << 7) | (b >> 4);
    const int c_half  = (b >> 3) & 1;
    const int m_base  = px_tile << 7;
    const float* fb = feat + (size_t)(m_base >> 14) * (CDIM * HW) + (m_base & (HW - 1));

    // ---- stage A: whole K, 4 groups of 64 k; reg-transpose fp32->bf16 ----
    const int sm0 = (t >> 3) << 2;   // px quad 0..124
    const int kb  = (t & 7) << 3;    // k base within group (8 k/thread)
    for (int g = 0; g < 4; ++g) {
        const float* fk = fb + (size_t)(g * 64 + kb) * HW + sm0;
        float av[8][4];
#pragma unroll
        for (int dk = 0; dk < 8; ++dk) {
            const float4 v = *reinterpret_cast<const float4*>(fk + (size_t)dk * HW);
            av[dk][0] = v.x; av[dk][1] = v.y; av[dk][2] = v.z; av[dk][3] = v.w;
        }
#pragma unroll
        for (int dm = 0; dm < 4; ++dm) {
            bf16x8 w;
#pragma unroll
            for (int dk = 0; dk < 8; ++dk) w[dk] = (short)f2bf(av[dk][dm]);
            *reinterpret_cast<bf16x8*>(
                ldsc + aswz(sm0 + dm, g * 128 + kb * 2)) = w;
        }
    }

    // ---- B prologue: wave's 32 c x 256 k of W1 -> 64 VGPR bf16 frags ----
    // bq is the MFMA first operand (M=c): lane&15 = c-row, k = kg*8 + j.
    const int cb = c_half * 128 + wid * 32;
    bf16x8 bq[2][8];
#pragma unroll
    for (int ni = 0; ni < 2; ++ni) {
        const float* wp = W1 + (size_t)(cb + ni * 16 + rr) * CDIM + kg * 8;
#pragma unroll
        for (int kk = 0; kk < 8; ++kk) {
            const float4 u = *reinterpret_cast<const float4*>(wp + kk * 32);
            const float4 v = *reinterpret_cast<const float4*>(wp + kk * 32 + 4);
            bf16x8 w;
            w[0] = (short)f2bf(u.x); w[1] = (short)f2bf(u.y);
            w[2] = (short)f2bf(u.z); w[3] = (short)f2bf(u.w);
            w[4] = (short)f2bf(v.x); w[5] = (short)f2bf(v.y);
            w[6] = (short)f2bf(v.z); w[7] = (short)f2bf(v.w);
            bq[ni][kk] = w;
        }
    }

    __syncthreads();   // the ONLY barrier

    // ---- main loop: 8 k-steps of pure ds_read_b128 + MFMA ----
    f32x4 acc[8][2] = {};
#pragma unroll
    for (int kk = 0; kk < 8; ++kk) {
        bf16x8 af[8];
#pragma unroll
        for (int mi = 0; mi < 8; ++mi)
            af[mi] = *reinterpret_cast<const bf16x8*>(
                ldsc + aswz(mi * 16 + rr, kk * 64 + kg * 16));
#pragma unroll
        for (int mi = 0; mi < 8; ++mi)
#pragma unroll
            for (int ni = 0; ni < 2; ++ni)
                acc[mi][ni] = __builtin_amdgcn_mfma_f32_16x16x32_bf16(
                    bq[ni][kk], af[mi], acc[mi][ni], 0, 0, 0);   // D[c][px]
    }

    // ---- epilogue: lane holds 4 consecutive c at fixed px -> 8B stores
    // (R4-proven pattern: WRITE_SIZE merged to exactly 64 MB in L2) ----
#pragma unroll
    for (int mi = 0; mi < 8; ++mi) {
        const int px = m_base + mi * 16 + rr;
#pragma unroll
        for (int ni = 0; ni < 2; ++ni) {
            const int c0 = cb + ni * 16 + kg * 4;
            uint2 v;
            v.x = (unsigned)f2bf(acc[mi][ni][0]) | ((unsigned)f2bf(acc[mi][ni][1]) << 16);
            v.y = (unsigned)f2bf(acc[mi][ni][2]) | ((unsigned)f2bf(acc[mi][ni][3]) << 16);
            *reinterpret_cast<uint2*>(f2t + (size_t)px * CDIM + c0) = v;
        }
    }
}

// One wave per sample point: bilinear-weighted sum of 4 contiguous 512B rows
// of F2t, then relu(s+b1) . W2 -> 2 scalars, out = batch_edges + d.
__global__ __launch_bounds__(256) void point_kernel(
    const unsigned short* __restrict__ f2t,
    const float* __restrict__ be,
    const float* __restrict__ b1, const float* __restrict__ W2,
    float* __restrict__ out) {
    const int p    = (blockIdx.x * 256 + threadIdx.x) >> 6;   // 0..65535
    const int lane = threadIdx.x & 63;

    const float ex = be[p * 2 + 0];
    const float ey = be[p * 2 + 1];
    const float gx = ex * (2.0f / 128.0f) - 1.0f;
    const float gy = ey * (2.0f / 128.0f) - 1.0f;
    const float px = (gx + 1.0f) * 64.0f - 0.5f;
    const float py = (gy + 1.0f) * 64.0f - 0.5f;
    const float x0f = floorf(px), y0f = floorf(py);
    const int   x0 = (int)x0f, y0 = (int)y0f;
    const float wx1 = px - x0f, wy1 = py - y0f;
    const float wx0 = 1.0f - wx1, wy0 = 1.0f - wy1;

    const size_t pix_base = (size_t)(p >> 13) * HW;
    const int c0 = lane * 4;

    float s0 = 0.f, s1 = 0.f, s2 = 0.f, s3 = 0.f;
#pragma unroll
    for (int cy = 0; cy < 2; ++cy) {
        const int   yi  = y0 + cy;
        const float wy  = cy ? wy1 : wy0;
        const bool  yin = (yi >= 0) && (yi < 128);
        const int   yc  = min(max(yi, 0), 127);
#pragma unroll
        for (int cx = 0; cx < 2; ++cx) {
            const int   xi  = x0 + cx;
            const float wx  = cx ? wx1 : wx0;
            const bool  xin = (xi >= 0) && (xi < 128);
            const int   xc  = min(max(xi, 0), 127);
            const float w   = wx * wy * (float)(xin && yin);
            const ushort4 v = *reinterpret_cast<const ushort4*>(
                &f2t[(pix_base + (size_t)yc * 128 + xc) * 256 + c0]);
            s0 += w * bf2f(v.x); s1 += w * bf2f(v.y);
            s2 += w * bf2f(v.z); s3 += w * bf2f(v.w);
        }
    }
    const float4 bb  = *reinterpret_cast<const float4*>(&b1[c0]);
    const float4 w2a = *reinterpret_cast<const float4*>(&W2[c0]);
    const float4 w2b = *reinterpret_cast<const float4*>(&W2[256 + c0]);
    const float h0 = fmaxf(s0 + bb.x, 0.f);
    const float h1 = fmaxf(s1 + bb.y, 0.f);
    const float h2 = fmaxf(s2 + bb.z, 0.f);
    const float h3 = fmaxf(s3 + bb.w, 0.f);
    float a0 = h0 * w2a.x + h1 * w2a.y + h2 * w2a.z + h3 * w2a.w;
    float a1 = h0 * w2b.x + h1 * w2b.y + h2 * w2b.z + h3 * w2b.w;
#pragma unroll
    for (int off = 32; off > 0; off >>= 1) {
        a0 += __shfl_xor(a0, off);
        a1 += __shfl_xor(a1, off);
    }
    if (lane == 0) {
        out[p * 2 + 0] = ex + a0;
        out[p * 2 + 1] = ey + a1;
    }
}

extern "C" void kernel_launch(void* const* d_in, const int* in_sizes, int n_in,
                              void* d_out, int out_size, void* d_ws, size_t ws_size,
                              hipStream_t stream) {
    const float* feat = (const float*)d_in[0];
    const float* be   = (const float*)d_in[1];
    const float* W1   = (const float*)d_in[2];
    const float* b1   = (const float*)d_in[3];
    const float* W2   = (const float*)d_in[4];
    float* out = (float*)d_out;
    unsigned short* f2t = (unsigned short*)d_ws;   // 131072*256 bf16 = 64 MiB

    f2_gemm<<<2048, 256, 0, stream>>>(feat, W1, f2t);
    point_kernel<<<16384, 256, 0, stream>>>(f2t, be, b1, W2, out);
}

// Round 9
// 79.581 us; speedup vs baseline: 4.7576x; 1.2159x over previous
//
#include <hip/hip_runtime.h>
#include <hip/hip_bf16.h>

typedef __attribute__((ext_vector_type(4))) float f32x4;
typedef __attribute__((ext_vector_type(8))) short bf16x8;

#define HW    16384   // 128*128
#define CDIM  256

__device__ __forceinline__ unsigned short f2bf(float x) {
    union { float f; unsigned u; } c; c.f = x;
    unsigned r = c.u + 0x7fffu + ((c.u >> 16) & 1u);   // RNE
    return (unsigned short)(r >> 16);
}
__device__ __forceinline__ float bf2f(unsigned short u) {
    union { unsigned u; float f; } c; c.u = ((unsigned)u) << 16;
    return c.f;
}

// A/B LDS tile: 128 rows x 64 k bf16, 128B rows.
// byte(row,k) = row*128 + ((k*2) ^ ((row&7)<<4))  -> measured 262K conflicts (R2).
__device__ __forceinline__ int tswz(int row, int kbyte) {
    return row * 128 + (kbyte ^ ((row & 7) << 4));
}

// F2t[pixel][c] = sum_k W1[c,k] * feat[k][pixel]  (bf16 out, channel-last)
// R2 champion kernel verbatim EXCEPT the grid map:
//   b = xcd + 8*n_half + 16*j  ->  m_tile = xcd*128 + j
// so an m-tile's two n-half siblings are 8 dispatch indices apart on the SAME
// XCD (R4/R7/R8-proven: FETCH 133 -> ~67 MB). Tests whether converting half
// the A-loads from HBM-miss (~900cy) to L2-hit (~200cy) helps the
// latency-bound staging chain.
__global__ __launch_bounds__(256, 2) void f2_gemm(
    const float* __restrict__ feat, const float* __restrict__ W1,
    unsigned short* __restrict__ f2t) {
    __shared__ short lds[16384];            // 32KB: A bytes [0,16384), B [16384,32768)
    char* const ldsc = (char*)lds;

    const int t      = threadIdx.x;
    const int b      = blockIdx.x;
    const int m_tile = ((b & 7) << 7) | (b >> 4);   // xcd*128 + j
    const int n_half = (b >> 3) & 1;
    const int m_base = m_tile << 7;
    const float* fb  = feat + (size_t)(m_base >> 14) * CDIM * HW + (m_base & (HW - 1));
    const float* wb  = W1 + (size_t)(n_half * 128) * CDIM;

    const int lane = t & 63;
    const int wid  = t >> 6;
    const int wm   = wid >> 1;           // 2 m-slabs of 64
    const int wn   = wid & 1;            // 2 n-slabs of 64

    const int sm0 = (t >> 3) << 2;       // staging row base 0..124 (A:m, B:c)
    const int kb  = (t & 7) << 3;        // staging k base 0..56 (8 k/thread)

    f32x4 acc[4][4] = {};
    float av[8][4];                      // A raw: [dk][dm]
    float bv[4][8];                      // B raw: [dc][dk]

    auto load_tile = [&](int kk) {
        const float* fk = fb + (size_t)(kk * 64 + kb) * HW + sm0;
#pragma unroll
        for (int dk = 0; dk < 8; ++dk) {
            const float4 v = *reinterpret_cast<const float4*>(fk + (size_t)dk * HW);
            av[dk][0] = v.x; av[dk][1] = v.y; av[dk][2] = v.z; av[dk][3] = v.w;
        }
        const float* wk = wb + (size_t)sm0 * CDIM + kk * 64 + kb;
#pragma unroll
        for (int dc = 0; dc < 4; ++dc) {
            const float4 u = *reinterpret_cast<const float4*>(wk + (size_t)dc * CDIM);
            const float4 w = *reinterpret_cast<const float4*>(wk + (size_t)dc * CDIM + 4);
            bv[dc][0] = u.x; bv[dc][1] = u.y; bv[dc][2] = u.z; bv[dc][3] = u.w;
            bv[dc][4] = w.x; bv[dc][5] = w.y; bv[dc][6] = w.z; bv[dc][7] = w.w;
        }
    };

    auto write_tile = [&]() {
#pragma unroll
        for (int dm = 0; dm < 4; ++dm) {           // A: transpose in regs
            const int row = sm0 + dm;
            bf16x8 w;
#pragma unroll
            for (int dk = 0; dk < 8; ++dk) w[dk] = (short)f2bf(av[dk][dm]);
            *reinterpret_cast<bf16x8*>(ldsc + tswz(row, kb * 2)) = w;
        }
#pragma unroll
        for (int dc = 0; dc < 4; ++dc) {           // B: k already contiguous
            const int row = sm0 + dc;
            bf16x8 w;
#pragma unroll
            for (int dk = 0; dk < 8; ++dk) w[dk] = (short)f2bf(bv[dc][dk]);
            *reinterpret_cast<bf16x8*>(ldsc + 16384 + tswz(row, kb * 2)) = w;
        }
    };

    auto compute = [&]() {
#pragma unroll
        for (int ks = 0; ks < 2; ++ks) {
            const int kb2 = ks * 64 + ((lane >> 4) << 4);   // byte offset of k*2
            bf16x8 af[4], bfr[4];
#pragma unroll
            for (int mi = 0; mi < 4; ++mi) {
                const int row = wm * 64 + mi * 16 + (lane & 15);
                af[mi] = *reinterpret_cast<const bf16x8*>(ldsc + tswz(row, kb2));
            }
#pragma unroll
            for (int ni = 0; ni < 4; ++ni) {
                const int c = wn * 64 + ni * 16 + (lane & 15);
                bfr[ni] = *reinterpret_cast<const bf16x8*>(ldsc + 16384 + tswz(c, kb2));
            }
#pragma unroll
            for (int mi = 0; mi < 4; ++mi)
#pragma unroll
                for (int ni = 0; ni < 4; ++ni)
                    acc[mi][ni] = __builtin_amdgcn_mfma_f32_16x16x32_bf16(
                        af[mi], bfr[ni], acc[mi][ni], 0, 0, 0);
        }
    };

    // prologue
    load_tile(0);
    write_tile();
    __syncthreads();
    // main loop: issue k+1 loads before compute(k), convert/write after
    for (int kk = 0; kk < 4; ++kk) {
        if (kk < 3) load_tile(kk + 1);
        compute();
        __syncthreads();
        if (kk < 3) { write_tile(); __syncthreads(); }
    }

    // ---- epilogue: acc -> bf16 -> LDS (swizzled) -> coalesced dwordx4 stores
#pragma unroll
    for (int mi = 0; mi < 4; ++mi)
#pragma unroll
        for (int ni = 0; ni < 4; ++ni) {
            const int c2 = (wn * 64 + ni * 16 + (lane & 15)) * 2;
#pragma unroll
            for (int r = 0; r < 4; ++r) {
                const int row = wm * 64 + mi * 16 + ((lane >> 4) << 2) + r;
                *reinterpret_cast<unsigned short*>(
                    ldsc + row * 256 + (c2 ^ (((row >> 2) & 3) << 5))) =
                    f2bf(acc[mi][ni][r]);
            }
        }
    __syncthreads();
#pragma unroll
    for (int i = 0; i < 8; ++i) {
        const int row = ((t >> 4) << 3) + i;
        const int cb  = (t & 15) * 16;
        const int4 v = *reinterpret_cast<const int4*>(
            ldsc + row * 256 + (cb ^ (((row >> 2) & 3) << 5)));
        *reinterpret_cast<int4*>((char*)f2t +
            (size_t)(m_base + row) * 512 + n_half * 256 + cb) = v;
    }
}

// One wave per sample point: bilinear-weighted sum of 4 contiguous 512B rows
// of F2t, then relu(s+b1) . W2 -> 2 scalars, out = batch_edges + d.
__global__ __launch_bounds__(256) void point_kernel(
    const unsigned short* __restrict__ f2t,
    const float* __restrict__ be,
    const float* __restrict__ b1, const float* __restrict__ W2,
    float* __restrict__ out) {
    const int p    = (blockIdx.x * 256 + threadIdx.x) >> 6;   // 0..65535
    const int lane = threadIdx.x & 63;

    const float ex = be[p * 2 + 0];
    const float ey = be[p * 2 + 1];
    const float gx = ex * (2.0f / 128.0f) - 1.0f;
    const float gy = ey * (2.0f / 128.0f) - 1.0f;
    const float px = (gx + 1.0f) * 64.0f - 0.5f;
    const float py = (gy + 1.0f) * 64.0f - 0.5f;
    const float x0f = floorf(px), y0f = floorf(py);
    const int   x0 = (int)x0f, y0 = (int)y0f;
    const float wx1 = px - x0f, wy1 = py - y0f;
    const float wx0 = 1.0f - wx1, wy0 = 1.0f - wy1;

    const size_t pix_base = (size_t)(p >> 13) * HW;
    const int c0 = lane * 4;

    float s0 = 0.f, s1 = 0.f, s2 = 0.f, s3 = 0.f;
#pragma unroll
    for (int cy = 0; cy < 2; ++cy) {
        const int   yi  = y0 + cy;
        const float wy  = cy ? wy1 : wy0;
        const bool  yin = (yi >= 0) && (yi < 128);
        const int   yc  = min(max(yi, 0), 127);
#pragma unroll
        for (int cx = 0; cx < 2; ++cx) {
            const int   xi  = x0 + cx;
            const float wx  = cx ? wx1 : wx0;
            const bool  xin = (xi >= 0) && (xi < 128);
            const int   xc  = min(max(xi, 0), 127);
            const float w   = wx * wy * (float)(xin && yin);
            const ushort4 v = *reinterpret_cast<const ushort4*>(
                &f2t[(pix_base + (size_t)yc * 128 + xc) * 256 + c0]);
            s0 += w * bf2f(v.x); s1 += w * bf2f(v.y);
            s2 += w * bf2f(v.z); s3 += w * bf2f(v.w);
        }
    }
    const float4 bb  = *reinterpret_cast<const float4*>(&b1[c0]);
    const float4 w2a = *reinterpret_cast<const float4*>(&W2[c0]);
    const float4 w2b = *reinterpret_cast<const float4*>(&W2[256 + c0]);
    const float h0 = fmaxf(s0 + bb.x, 0.f);
    const float h1 = fmaxf(s1 + bb.y, 0.f);
    const float h2 = fmaxf(s2 + bb.z, 0.f);
    const float h3 = fmaxf(s3 + bb.w, 0.f);
    float a0 = h0 * w2a.x + h1 * w2a.y + h2 * w2a.z + h3 * w2a.w;
    float a1 = h0 * w2b.x + h1 * w2b.y + h2 * w2b.z + h3 * w2b.w;
#pragma unroll
    for (int off = 32; off > 0; off >>= 1) {
        a0 += __shfl_xor(a0, off);
        a1 += __shfl_xor(a1, off);
    }
    if (lane == 0) {
        out[p * 2 + 0] = ex + a0;
        out[p * 2 + 1] = ey + a1;
    }
}

extern "C" void kernel_launch(void* const* d_in, const int* in_sizes, int n_in,
                              void* d_out, int out_size, void* d_ws, size_t ws_size,
                              hipStream_t stream) {
    const float* feat = (const float*)d_in[0];
    const float* be   = (const float*)d_in[1];
    const float* W1   = (const float*)d_in[2];
    const float* b1   = (const float*)d_in[3];
    const float* W2   = (const float*)d_in[4];
    float* out = (float*)d_out;
    unsigned short* f2t = (unsigned short*)d_ws;   // 131072*256 bf16 = 64 MiB

    f2_gemm<<<2048, 256, 0, stream>>>(feat, W1, f2t);
    point_kernel<<<16384, 256, 0, stream>>>(f2t, be, b1, W2, out);
}